// Round 4
// baseline (256.815 us; speedup 1.0000x reference)
//
#include <hip/hip_runtime.h>

// ---------- types ----------
typedef __attribute__((ext_vector_type(8))) short short8;
typedef __attribute__((ext_vector_type(8), may_alias)) short short8a;
typedef __attribute__((ext_vector_type(4))) short short4a_ __attribute__((may_alias));
typedef __attribute__((ext_vector_type(2), may_alias)) short short2a;
typedef __attribute__((ext_vector_type(4))) float float4_;
typedef __attribute__((ext_vector_type(4), may_alias)) float float4a;

__device__ __forceinline__ float b2f(short h) {
  unsigned int u = ((unsigned int)(unsigned short)h) << 16;
  return __builtin_bit_cast(float, u);
}
__device__ __forceinline__ short f2b(float f) {
  unsigned int u = __builtin_bit_cast(unsigned int, f);
  u += 0x7fffu + ((u >> 16) & 1u);   // RNE
  return (short)(unsigned short)(u >> 16);
}

#define GLOBAL_AS __attribute__((address_space(1)))
#define LDS_AS    __attribute__((address_space(3)))
__device__ __forceinline__ void async_copy16(void* lds, const void* g) {
  __builtin_amdgcn_global_load_lds((GLOBAL_AS const void*)g, (LDS_AS void*)lds, 16, 0, 0);
}

// ---------- 1. fused prep: x->bf16, Wq|Wk|Wv transpose (q-scale folded), Wo transpose ----------
// grid: [0,1536) wqkv tiles, [1536,2560) wo tiles, [2560,10752) cvt blocks
__global__ __launch_bounds__(256) void prep(const float* __restrict__ x,
                                            const float* __restrict__ Wq,
                                            const float* __restrict__ Wk,
                                            const float* __restrict__ Wv,
                                            const float* __restrict__ Wo,
                                            short* __restrict__ xb,
                                            short* __restrict__ wqkvt,
                                            short* __restrict__ wot) {
  __shared__ float tile[64][65];
  int bid = blockIdx.x;
  if (bid < 1536) {                     // Wq|Wk|Wv -> [3072][2048] bf16 (B^T)
    int k0 = (bid & 31) * 64, n0 = (bid >> 5) * 64;
    for (int idx = threadIdx.x; idx < 4096; idx += 256) {
      int r = idx >> 6, cc = idx & 63;
      int n = n0 + cc;
      float v;
      if (n < 2048)      v = Wq[(size_t)(k0 + r) * 2048 + n] * 0.08838834764831845f; // fold 1/sqrt(128)
      else if (n < 2560) v = Wk[(size_t)(k0 + r) * 512 + (n - 2048)];
      else               v = Wv[(size_t)(k0 + r) * 512 + (n - 2560)];
      tile[r][cc] = v;
    }
    __syncthreads();
    for (int idx = threadIdx.x; idx < 4096; idx += 256) {
      int r = idx >> 6, cc = idx & 63;
      wqkvt[(size_t)(n0 + r) * 2048 + k0 + cc] = f2b(tile[cc][r]);
    }
  } else if (bid < 2560) {              // Wo -> [2048][2048] bf16 (B^T)
    int t = bid - 1536;
    int k0 = (t & 31) * 64, n0 = (t >> 5) * 64;
    for (int idx = threadIdx.x; idx < 4096; idx += 256) {
      int r = idx >> 6, cc = idx & 63;
      tile[r][cc] = Wo[(size_t)(k0 + r) * 2048 + n0 + cc];
    }
    __syncthreads();
    for (int idx = threadIdx.x; idx < 4096; idx += 256) {
      int r = idx >> 6, cc = idx & 63;
      wot[(size_t)(n0 + r) * 2048 + k0 + cc] = f2b(tile[cc][r]);
    }
  } else {                              // x fp32 -> bf16
    int i = (bid - 2560) * 256 + threadIdx.x;
    float4a v = ((const float4a*)x)[i];
    short4a_ o;
    o.x = f2b(v.x); o.y = f2b(v.y); o.z = f2b(v.z); o.w = f2b(v.w);
    ((short4a_*)xb)[i] = o;
  }
}

// ---------- 2. GEMM  C[M][N] = A[M][K] * B^T[N][K] ----------
// MODE 0: fp32 direct store. MODE 1: bf16 out; n0<2560 -> fused RoPE via LDS; n0>=2560 -> direct.
// 128x128 tile, BK=64, global_load_lds(16B), XOR chunk swizzle (chunk' = chunk ^ (row&7))
template <int MODE>
__global__ __launch_bounds__(256, 2)
void gemm_bt(const short* __restrict__ A, const short* __restrict__ B,
             void* __restrict__ Cv, int M, int N, int K) {
  __shared__ alignas(16) short lsm[MODE == 1 ? 16896 : 16384];
  short* lA = lsm;
  short* lB = lsm + 8192;
  const int tid = threadIdx.x;
  const int wave = tid >> 6, lane = tid & 63;
  const int quad = lane >> 4, l16 = lane & 15;
  const int m0 = blockIdx.x * 128, n0 = blockIdx.y * 128;
  const int wm = (wave >> 1) * 64, wn = (wave & 1) * 64;
  float4_ acc[4][4];
#pragma unroll
  for (int i = 0; i < 4; i++)
#pragma unroll
    for (int j = 0; j < 4; j++) acc[i][j] = (float4_){0.f, 0.f, 0.f, 0.f};
  const int nK = K >> 6;
  const int srow = lane >> 3, slot = lane & 7;
  for (int kt = 0; kt < nK; ++kt) {
    __syncthreads();
#pragma unroll
    for (int cth = 0; cth < 4; ++cth) {
      int rb = wave * 32 + cth * 8;
      int r = rb + srow;
      int c = slot ^ (r & 7);
      async_copy16(&lA[rb * 64], A + (size_t)(m0 + r) * K + kt * 64 + c * 8);
      async_copy16(&lB[rb * 64], B + (size_t)(n0 + r) * K + kt * 64 + c * 8);
    }
    __syncthreads();
#pragma unroll
    for (int kc = 0; kc < 2; ++kc) {
      short8 af[4], bf[4];
      int cch = kc * 4 + quad;
#pragma unroll
      for (int mt = 0; mt < 4; ++mt) {
        int ar = wm + mt * 16 + l16;
        af[mt] = *(const short8a*)&lA[ar * 64 + (cch ^ (ar & 7)) * 8];
      }
#pragma unroll
      for (int nt = 0; nt < 4; ++nt) {
        int br = wn + nt * 16 + l16;
        bf[nt] = *(const short8a*)&lB[br * 64 + (cch ^ (br & 7)) * 8];
      }
#pragma unroll
      for (int mt = 0; mt < 4; ++mt)
#pragma unroll
        for (int nt = 0; nt < 4; ++nt)
          acc[mt][nt] = __builtin_amdgcn_mfma_f32_16x16x32_bf16(af[mt], bf[nt], acc[mt][nt], 0, 0, 0);
    }
  }
  if (MODE == 1 && n0 < 2560) {
    // ---- fused RoPE epilogue (Q and K blocks; each block = one head's 128 dims) ----
    __syncthreads();                    // staging LDS now dead
    short* lC = lsm;                    // [128][132] bf16
#pragma unroll
    for (int mt = 0; mt < 4; ++mt)
#pragma unroll
      for (int nt = 0; nt < 4; ++nt)
#pragma unroll
        for (int r = 0; r < 4; r++)
          lC[(wm + mt * 16 + quad * 4 + r) * 132 + wn + nt * 16 + l16] = f2b(acc[mt][nt][r]);
    __syncthreads();
    short* Cb = (short*)Cv;
    const int posBase = m0 & 1023;
#pragma unroll
    for (int it = 0; it < 16; ++it) {
      int idx = it * 256 + tid;         // 0..4095
      int row = idx >> 5;               // 0..127
      int c2 = (idx & 31) * 2;          // pair indices c2, c2+1 (in [0,64))
      float t1a = b2f(lC[row * 132 + c2]),      t1b = b2f(lC[row * 132 + c2 + 1]);
      float t2a = b2f(lC[row * 132 + c2 + 64]), t2b = b2f(lC[row * 132 + c2 + 65]);
      float pos = (float)(posBase + row);
      float sa, ca, sb, cb;
      sincosf(pos * exp2f((float)c2 * -0.20762050593478f), &sa, &ca);
      sincosf(pos * exp2f((float)(c2 + 1) * -0.20762050593478f), &sb, &cb);
      short2a o1, o2;
      o1.x = f2b(t1a * ca - t2a * sa); o1.y = f2b(t1b * cb - t2b * sb);
      o2.x = f2b(t2a * ca + t1a * sa); o2.y = f2b(t2b * cb + t1b * sb);
      size_t base = (size_t)(m0 + row) * N + n0;
      *(short2a*)&Cb[base + c2] = o1;
      *(short2a*)&Cb[base + c2 + 64] = o2;
    }
  } else {
#pragma unroll
    for (int mt = 0; mt < 4; ++mt)
#pragma unroll
      for (int nt = 0; nt < 4; ++nt) {
        int row = m0 + wm + mt * 16 + quad * 4;
        int col = n0 + wn + nt * 16 + l16;
        float4_ v = acc[mt][nt];
        if (MODE == 1) {
          short* Cb = (short*)Cv;
#pragma unroll
          for (int r = 0; r < 4; r++) Cb[(size_t)(row + r) * N + col] = f2b(v[r]);
        } else {
          float* Cf = (float*)Cv;
#pragma unroll
          for (int r = 0; r < 4; r++) Cf[(size_t)(row + r) * N + col] = v[r];
        }
      }
  }
}

// ---------- 3. build V^T: vt[(b*4+kv)*128+d][n] = qkv[b*1024+n][2560+kv*128+d] ----------
__global__ __launch_bounds__(256) void vt_build(const short* __restrict__ qkv, short* __restrict__ vt) {
  __shared__ short tile[128][65];   // [d][n], padded
  int bkv = blockIdx.x, n0 = blockIdx.y * 64;
  int b = bkv >> 2, kv = bkv & 3;
  const short* src = qkv + (size_t)(b * 1024) * 3072 + 2560 + kv * 128;
#pragma unroll
  for (int it = 0; it < 4; ++it) {
    int n = it * 16 + (threadIdx.x >> 4), ch = threadIdx.x & 15;
    short8a v = *(const short8a*)(src + (size_t)(n0 + n) * 3072 + ch * 8);
#pragma unroll
    for (int j = 0; j < 8; ++j) tile[ch * 8 + j][n] = v[j];
  }
  __syncthreads();
#pragma unroll
  for (int it = 0; it < 4; ++it) {
    int idx = it * 256 + threadIdx.x;   // 0..1023
    int d = idx >> 3, ch = idx & 7;
    short8a v;
#pragma unroll
    for (int j = 0; j < 8; ++j) v[j] = tile[d][ch * 8 + j];
    *(short8a*)(vt + (size_t)(bkv * 128 + d) * 1024 + n0 + ch * 8) = v;
  }
}

// ---------- 4. GQA causal flash attention (no-max softmax; 128-row Q tiles) ----------
// grid (64 = b*16+h, 8 qtiles reversed), 256 threads = 4 waves x (2 groups x 16 q-rows)
__global__ __launch_bounds__(256, 2)
void flash(const short* __restrict__ qkv, const short* __restrict__ vt,
           const float* __restrict__ head_scale, short* __restrict__ attn) {
  __shared__ alignas(16) short lK[64 * 128];   // [krow][d-chunk swizzled]
  __shared__ alignas(16) short lV[128 * 64];   // [d][krow-chunk swizzled]
  __shared__ alignas(16) short lP[4][32 * 72]; // per-wave P (32 rows), padded stride 72
  const int tid = threadIdx.x, wave = tid >> 6, lane = tid & 63;
  const int quad = lane >> 4, l16 = lane & 15;
  const int bh = blockIdx.x, b = bh >> 4, h = bh & 15, kv = h >> 2;
  const int qt = 7 - blockIdx.y;               // heavy blocks first
  const int base_w = qt * 128 + wave * 32;     // wave's first q-row
  short8 qf[2][4];
#pragma unroll
  for (int g = 0; g < 2; g++) {
    int qrow = base_w + g * 16 + l16;
    const short* qp = qkv + (size_t)(b * 1024 + qrow) * 3072 + h * 128;
#pragma unroll
    for (int kc = 0; kc < 4; kc++) qf[g][kc] = *(const short8a*)(qp + kc * 32 + quad * 8);
  }
  float4_ O[2][8];
#pragma unroll
  for (int g = 0; g < 2; g++)
#pragma unroll
    for (int i = 0; i < 8; i++) O[g][i] = (float4_){0.f, 0.f, 0.f, 0.f};
  float rsacc[2][4] = {{0.f, 0.f, 0.f, 0.f}, {0.f, 0.f, 0.f, 0.f}};
  const size_t kbase = (size_t)(b * 1024) * 3072 + 2048 + kv * 128;
  const size_t vbase = (size_t)((b * 4 + kv) * 128) * 1024;
  const int slot16 = lane & 15, rr4 = lane >> 4;
  const int slot8 = lane & 7, dr8 = lane >> 3;
  const int nkt = 2 * qt + 2;
  for (int kt = 0; kt < nkt; ++kt) {
    __syncthreads();
#pragma unroll
    for (int cc = 0; cc < 4; ++cc) {           // K tile: 64 rows x 128 d
      int rb = wave * 16 + cc * 4;
      int r = rb + rr4;
      int c = slot16 ^ (r & 15);
      async_copy16(&lK[rb * 128], qkv + kbase + (size_t)(kt * 64 + r) * 3072 + c * 8);
    }
#pragma unroll
    for (int cc = 0; cc < 4; ++cc) {           // V tile: 128 d x 64 rows
      int db = wave * 32 + cc * 8;
      int d = db + dr8;
      int c = slot8 ^ (d & 7);
      async_copy16(&lV[db * 64], vt + vbase + (size_t)d * 1024 + kt * 64 + c * 8);
    }
    __syncthreads();
    if (kt * 64 > base_w + 31) continue;       // wave fully below diagonal (uniform)
    // S = Q K^T, both groups share kf
    float4_ S[2][4];
#pragma unroll
    for (int st = 0; st < 4; ++st) {
      float4_ s0 = (float4_){0.f, 0.f, 0.f, 0.f}, s1 = s0;
      int kr = st * 16 + l16;
#pragma unroll
      for (int kc = 0; kc < 4; ++kc) {
        int c = kc * 4 + quad;
        short8 kf = *(const short8a*)&lK[kr * 128 + (c ^ (kr & 15)) * 8];
        s0 = __builtin_amdgcn_mfma_f32_16x16x32_bf16(qf[0][kc], kf, s0, 0, 0, 0);
        s1 = __builtin_amdgcn_mfma_f32_16x16x32_bf16(qf[1][kc], kf, s1, 0, 0, 0);
      }
      S[0][st] = s0; S[1][st] = s1;
    }
    // causal mask + exp + P store
#pragma unroll
    for (int g = 0; g < 2; g++) {
      int gbase = base_w + g * 16;
      if (kt * 64 + 63 > gbase) {
#pragma unroll
        for (int st = 0; st < 4; ++st)
#pragma unroll
          for (int r = 0; r < 4; r++)
            if (kt * 64 + st * 16 + l16 > gbase + quad * 4 + r) S[g][st][r] = -1e30f;
      }
#pragma unroll
      for (int st = 0; st < 4; ++st)
#pragma unroll
        for (int r = 0; r < 4; r++) {
          float pv = __expf(S[g][st][r]);
          rsacc[g][r] += pv;
          lP[wave][(g * 16 + quad * 4 + r) * 72 + st * 16 + l16] = f2b(pv);
        }
    }
    short8 pf[2][2];
#pragma unroll
    for (int g = 0; g < 2; g++)
#pragma unroll
      for (int kc2 = 0; kc2 < 2; kc2++)
        pf[g][kc2] = *(const short8a*)&lP[wave][(g * 16 + l16) * 72 + kc2 * 32 + quad * 8];
#pragma unroll
    for (int dt = 0; dt < 8; ++dt) {
      int d = dt * 16 + l16;
#pragma unroll
      for (int kc2 = 0; kc2 < 2; kc2++) {
        int c = kc2 * 4 + quad;
        short8 vf = *(const short8a*)&lV[d * 64 + (c ^ (d & 7)) * 8];
        O[0][dt] = __builtin_amdgcn_mfma_f32_16x16x32_bf16(pf[0][kc2], vf, O[0][dt], 0, 0, 0);
        O[1][dt] = __builtin_amdgcn_mfma_f32_16x16x32_bf16(pf[1][kc2], vf, O[1][dt], 0, 0, 0);
      }
    }
  }
  float hs = head_scale[h];
#pragma unroll
  for (int g = 0; g < 2; g++) {
    float l_i[4];
#pragma unroll
    for (int r = 0; r < 4; r++) {
      float rs = rsacc[g][r];
#pragma unroll
      for (int off = 8; off; off >>= 1) rs += __shfl_xor(rs, off, 64);
      l_i[r] = rs;
    }
    int qrow = base_w + g * 16 + quad * 4;
#pragma unroll
    for (int dt = 0; dt < 8; ++dt) {
      int col = h * 128 + dt * 16 + l16;
#pragma unroll
      for (int r = 0; r < 4; r++) {
        float o = O[g][dt][r] * (hs / l_i[r]);
        attn[(size_t)(b * 1024 + qrow + r) * 2048 + col] = f2b(o);
      }
    }
  }
}

// ---------- launch ----------
extern "C" void kernel_launch(void* const* d_in, const int* in_sizes, int n_in,
                              void* d_out, int out_size, void* d_ws, size_t ws_size,
                              hipStream_t stream) {
  const float* x  = (const float*)d_in[0];
  const float* Wq = (const float*)d_in[1];
  const float* Wk = (const float*)d_in[2];
  const float* Wv = (const float*)d_in[3];
  const float* Wo = (const float*)d_in[4];
  const float* hs = (const float*)d_in[5];
  float* out = (float*)d_out;
  char* ws = (char*)d_ws;
  // ws layout (64 MB total)
  short* xb    = (short*)(ws);                  // 16 MB  [4096][2048]   (reused as attn)
  short* wqkvt = (short*)(ws + 16777216);       // 12 MB  [3072][2048]
  short* wot   = (short*)(ws + 29360128);       //  8 MB  [2048][2048]
  short* qkv   = (short*)(ws + 37748736);       // 24 MB  [4096][3072]
  short* vt    = (short*)(ws + 62914560);       //  4 MB  [2048][1024]
  short* attn  = xb;                            // alias: xb dead after GEMM1

  prep<<<10752, 256, 0, stream>>>(x, Wq, Wk, Wv, Wo, xb, wqkvt, wot);
  gemm_bt<1><<<dim3(32, 24), 256, 0, stream>>>(xb, wqkvt, (void*)qkv, 4096, 3072, 2048);
  vt_build<<<dim3(16, 16), 256, 0, stream>>>(qkv, vt);
  flash<<<dim3(64, 8), 256, 0, stream>>>(qkv, vt, hs, attn);
  gemm_bt<0><<<dim3(32, 16), 256, 0, stream>>>(attn, wot, (void*)out, 4096, 2048, 2048);
}

// Round 5
// 253.567 us; speedup vs baseline: 1.0128x; 1.0128x over previous
//
#include <hip/hip_runtime.h>

// ---------- types ----------
typedef __attribute__((ext_vector_type(8))) short short8;
typedef __attribute__((ext_vector_type(8), may_alias)) short short8a;
typedef __attribute__((ext_vector_type(4))) short short4a_ __attribute__((may_alias));
typedef __attribute__((ext_vector_type(2), may_alias)) short short2a;
typedef __attribute__((ext_vector_type(4))) float float4_;
typedef __attribute__((ext_vector_type(4), may_alias)) float float4a;
typedef __attribute__((ext_vector_type(2), may_alias)) float float2a;

__device__ __forceinline__ float b2f(short h) {
  unsigned int u = ((unsigned int)(unsigned short)h) << 16;
  return __builtin_bit_cast(float, u);
}
__device__ __forceinline__ short f2b(float f) {
  unsigned int u = __builtin_bit_cast(unsigned int, f);
  u += 0x7fffu + ((u >> 16) & 1u);   // RNE
  return (short)(unsigned short)(u >> 16);
}

#define GLOBAL_AS __attribute__((address_space(1)))
#define LDS_AS    __attribute__((address_space(3)))
__device__ __forceinline__ void async_copy16(void* lds, const void* g) {
  __builtin_amdgcn_global_load_lds((GLOBAL_AS const void*)g, (LDS_AS void*)lds, 16, 0, 0);
}

// ---------- 1. fused prep: x->bf16, Wq|Wk|Wv transpose (q-scale folded), Wo transpose, rope table ----------
// grid: [0,1536) wqkv tiles, [1536,2560) wo tiles, [2560,10752) cvt blocks, [10752,11008) rope table
__global__ __launch_bounds__(256) void prep(const float* __restrict__ x,
                                            const float* __restrict__ Wq,
                                            const float* __restrict__ Wk,
                                            const float* __restrict__ Wv,
                                            const float* __restrict__ Wo,
                                            short* __restrict__ xb,
                                            short* __restrict__ wqkvt,
                                            short* __restrict__ wot,
                                            float* __restrict__ rtab) {
  __shared__ float tile[64][65];
  int bid = blockIdx.x;
  if (bid < 1536) {                     // Wq|Wk|Wv -> [3072][2048] bf16 (B^T)
    int k0 = (bid & 31) * 64, n0 = (bid >> 5) * 64;
    for (int idx = threadIdx.x; idx < 4096; idx += 256) {
      int r = idx >> 6, cc = idx & 63;
      int n = n0 + cc;
      float v;
      if (n < 2048)      v = Wq[(size_t)(k0 + r) * 2048 + n] * 0.08838834764831845f; // fold 1/sqrt(128)
      else if (n < 2560) v = Wk[(size_t)(k0 + r) * 512 + (n - 2048)];
      else               v = Wv[(size_t)(k0 + r) * 512 + (n - 2560)];
      tile[r][cc] = v;
    }
    __syncthreads();
    for (int idx = threadIdx.x; idx < 4096; idx += 256) {
      int r = idx >> 6, cc = idx & 63;
      wqkvt[(size_t)(n0 + r) * 2048 + k0 + cc] = f2b(tile[cc][r]);
    }
  } else if (bid < 2560) {              // Wo -> [2048][2048] bf16 (B^T)
    int t = bid - 1536;
    int k0 = (t & 31) * 64, n0 = (t >> 5) * 64;
    for (int idx = threadIdx.x; idx < 4096; idx += 256) {
      int r = idx >> 6, cc = idx & 63;
      tile[r][cc] = Wo[(size_t)(k0 + r) * 2048 + n0 + cc];
    }
    __syncthreads();
    for (int idx = threadIdx.x; idx < 4096; idx += 256) {
      int r = idx >> 6, cc = idx & 63;
      wot[(size_t)(n0 + r) * 2048 + k0 + cc] = f2b(tile[cc][r]);
    }
  } else if (bid < 10752) {             // x fp32 -> bf16
    int i = (bid - 2560) * 256 + threadIdx.x;
    float4a v = ((const float4a*)x)[i];
    short4a_ o;
    o.x = f2b(v.x); o.y = f2b(v.y); o.z = f2b(v.z); o.w = f2b(v.w);
    ((short4a_*)xb)[i] = o;
  } else {                              // rope table: rtab[(pos*64+i)*2] = {cos, sin}
    int idx = (bid - 10752) * 256 + threadIdx.x;   // 0..65535
    int pos = idx >> 6, i = idx & 63;
    float inv = exp2f((float)i * -0.20762050593478f);  // 10000^(-2i/128)
    float s, c;
    sincosf((float)pos * inv, &s, &c);
    float2a cs; cs.x = c; cs.y = s;
    ((float2a*)rtab)[idx] = cs;
  }
}

// ---------- 2. GEMM  C[M][N] = A[M][K] * B^T[N][K] ----------
// MODE 0: fp32 direct store. MODE 1: bf16 out; n0<2560 -> fused RoPE via LDS + table; n0>=2560 -> direct.
// 128x128 tile, BK=64, global_load_lds(16B), XOR chunk swizzle (chunk' = chunk ^ (row&7))
template <int MODE>
__global__ __launch_bounds__(256, 2)
void gemm_bt(const short* __restrict__ A, const short* __restrict__ B,
             void* __restrict__ Cv, const float* __restrict__ rtab, int M, int N, int K) {
  __shared__ alignas(16) short lsm[MODE == 1 ? 16896 : 16384];
  short* lA = lsm;
  short* lB = lsm + 8192;
  const int tid = threadIdx.x;
  const int wave = tid >> 6, lane = tid & 63;
  const int quad = lane >> 4, l16 = lane & 15;
  const int m0 = blockIdx.x * 128, n0 = blockIdx.y * 128;
  const int wm = (wave >> 1) * 64, wn = (wave & 1) * 64;
  float4_ acc[4][4];
#pragma unroll
  for (int i = 0; i < 4; i++)
#pragma unroll
    for (int j = 0; j < 4; j++) acc[i][j] = (float4_){0.f, 0.f, 0.f, 0.f};
  const int nK = K >> 6;
  const int srow = lane >> 3, slot = lane & 7;
  for (int kt = 0; kt < nK; ++kt) {
    __syncthreads();
#pragma unroll
    for (int cth = 0; cth < 4; ++cth) {
      int rb = wave * 32 + cth * 8;
      int r = rb + srow;
      int c = slot ^ (r & 7);
      async_copy16(&lA[rb * 64], A + (size_t)(m0 + r) * K + kt * 64 + c * 8);
      async_copy16(&lB[rb * 64], B + (size_t)(n0 + r) * K + kt * 64 + c * 8);
    }
    __syncthreads();
#pragma unroll
    for (int kc = 0; kc < 2; ++kc) {
      short8 af[4], bf[4];
      int cch = kc * 4 + quad;
#pragma unroll
      for (int mt = 0; mt < 4; ++mt) {
        int ar = wm + mt * 16 + l16;
        af[mt] = *(const short8a*)&lA[ar * 64 + (cch ^ (ar & 7)) * 8];
      }
#pragma unroll
      for (int nt = 0; nt < 4; ++nt) {
        int br = wn + nt * 16 + l16;
        bf[nt] = *(const short8a*)&lB[br * 64 + (cch ^ (br & 7)) * 8];
      }
#pragma unroll
      for (int mt = 0; mt < 4; ++mt)
#pragma unroll
        for (int nt = 0; nt < 4; ++nt)
          acc[mt][nt] = __builtin_amdgcn_mfma_f32_16x16x32_bf16(af[mt], bf[nt], acc[mt][nt], 0, 0, 0);
    }
  }
  if (MODE == 1 && n0 < 2560) {
    // ---- fused RoPE epilogue (Q and K blocks; each block = one head's 128 dims) ----
    __syncthreads();                    // staging LDS now dead
    short* lC = lsm;                    // [128][132] bf16
#pragma unroll
    for (int mt = 0; mt < 4; ++mt)
#pragma unroll
      for (int nt = 0; nt < 4; ++nt)
#pragma unroll
        for (int r = 0; r < 4; r++)
          lC[(wm + mt * 16 + quad * 4 + r) * 132 + wn + nt * 16 + l16] = f2b(acc[mt][nt][r]);
    __syncthreads();
    short* Cb = (short*)Cv;
    const int posBase = m0 & 1023;
#pragma unroll
    for (int it = 0; it < 16; ++it) {
      int idx = it * 256 + tid;         // 0..4095
      int row = idx >> 5;               // 0..127
      int c2 = (idx & 31) * 2;          // pair indices c2, c2+1 (in [0,64))
      short2a t1 = *(const short2a*)&lC[row * 132 + c2];
      short2a t2 = *(const short2a*)&lC[row * 132 + c2 + 64];
      float t1a = b2f(t1.x), t1b = b2f(t1.y);
      float t2a = b2f(t2.x), t2b = b2f(t2.y);
      float4a tv = *(const float4a*)&rtab[((size_t)(posBase + row) * 64 + c2) * 2]; // ca,sa,cb,sb
      short2a o1, o2;
      o1.x = f2b(t1a * tv.x - t2a * tv.y); o1.y = f2b(t1b * tv.z - t2b * tv.w);
      o2.x = f2b(t2a * tv.x + t1a * tv.y); o2.y = f2b(t2b * tv.z + t1b * tv.w);
      size_t base = (size_t)(m0 + row) * N + n0;
      *(short2a*)&Cb[base + c2] = o1;
      *(short2a*)&Cb[base + c2 + 64] = o2;
    }
  } else {
#pragma unroll
    for (int mt = 0; mt < 4; ++mt)
#pragma unroll
      for (int nt = 0; nt < 4; ++nt) {
        int row = m0 + wm + mt * 16 + quad * 4;
        int col = n0 + wn + nt * 16 + l16;
        float4_ v = acc[mt][nt];
        if (MODE == 1) {
          short* Cb = (short*)Cv;
#pragma unroll
          for (int r = 0; r < 4; r++) Cb[(size_t)(row + r) * N + col] = f2b(v[r]);
        } else {
          float* Cf = (float*)Cv;
#pragma unroll
          for (int r = 0; r < 4; r++) Cf[(size_t)(row + r) * N + col] = v[r];
        }
      }
  }
}

// ---------- 3. build V^T: vt[(b*4+kv)*128+d][n] = qkv[b*1024+n][2560+kv*128+d] ----------
__global__ __launch_bounds__(256) void vt_build(const short* __restrict__ qkv, short* __restrict__ vt) {
  __shared__ short tile[128][65];   // [d][n], padded
  int bkv = blockIdx.x, n0 = blockIdx.y * 64;
  int b = bkv >> 2, kv = bkv & 3;
  const short* src = qkv + (size_t)(b * 1024) * 3072 + 2560 + kv * 128;
#pragma unroll
  for (int it = 0; it < 4; ++it) {
    int n = it * 16 + (threadIdx.x >> 4), ch = threadIdx.x & 15;
    short8a v = *(const short8a*)(src + (size_t)(n0 + n) * 3072 + ch * 8);
#pragma unroll
    for (int j = 0; j < 8; ++j) tile[ch * 8 + j][n] = v[j];
  }
  __syncthreads();
#pragma unroll
  for (int it = 0; it < 4; ++it) {
    int idx = it * 256 + threadIdx.x;   // 0..1023
    int d = idx >> 3, ch = idx & 7;
    short8a v;
#pragma unroll
    for (int j = 0; j < 8; ++j) v[j] = tile[d][ch * 8 + j];
    *(short8a*)(vt + (size_t)(bkv * 128 + d) * 1024 + n0 + ch * 8) = v;
  }
}

// ---------- 4. GQA causal flash attention (no-max softmax; 128-row Q tiles) ----------
// grid (64 = b*16+h, 8 qtiles reversed), 256 threads = 4 waves x (2 groups x 16 q-rows)
__global__ __launch_bounds__(256, 2)
void flash(const short* __restrict__ qkv, const short* __restrict__ vt,
           const float* __restrict__ head_scale, short* __restrict__ attn) {
  __shared__ alignas(16) short lK[64 * 128];   // [krow][d-chunk swizzled]
  __shared__ alignas(16) short lV[128 * 64];   // [d][krow-chunk swizzled]
  __shared__ alignas(16) short lP[4][32 * 72]; // per-wave P (32 rows), padded stride 72
  const int tid = threadIdx.x, wave = tid >> 6, lane = tid & 63;
  const int quad = lane >> 4, l16 = lane & 15;
  const int bh = blockIdx.x, b = bh >> 4, h = bh & 15, kv = h >> 2;
  const int qt = 7 - blockIdx.y;               // heavy blocks first
  const int base_w = qt * 128 + wave * 32;     // wave's first q-row
  short8 qf[2][4];
#pragma unroll
  for (int g = 0; g < 2; g++) {
    int qrow = base_w + g * 16 + l16;
    const short* qp = qkv + (size_t)(b * 1024 + qrow) * 3072 + h * 128;
#pragma unroll
    for (int kc = 0; kc < 4; kc++) qf[g][kc] = *(const short8a*)(qp + kc * 32 + quad * 8);
  }
  float4_ O[2][8];
#pragma unroll
  for (int g = 0; g < 2; g++)
#pragma unroll
    for (int i = 0; i < 8; i++) O[g][i] = (float4_){0.f, 0.f, 0.f, 0.f};
  float rsacc[2][4] = {{0.f, 0.f, 0.f, 0.f}, {0.f, 0.f, 0.f, 0.f}};
  const size_t kbase = (size_t)(b * 1024) * 3072 + 2048 + kv * 128;
  const size_t vbase = (size_t)((b * 4 + kv) * 128) * 1024;
  const int slot16 = lane & 15, rr4 = lane >> 4;
  const int slot8 = lane & 7, dr8 = lane >> 3;
  const int nkt = 2 * qt + 2;
  for (int kt = 0; kt < nkt; ++kt) {
    __syncthreads();
#pragma unroll
    for (int cc = 0; cc < 4; ++cc) {           // K tile: 64 rows x 128 d
      int rb = wave * 16 + cc * 4;
      int r = rb + rr4;
      int c = slot16 ^ (r & 15);
      async_copy16(&lK[rb * 128], qkv + kbase + (size_t)(kt * 64 + r) * 3072 + c * 8);
    }
#pragma unroll
    for (int cc = 0; cc < 4; ++cc) {           // V tile: 128 d x 64 rows
      int db = wave * 32 + cc * 8;
      int d = db + dr8;
      int c = slot8 ^ (d & 7);
      async_copy16(&lV[db * 64], vt + vbase + (size_t)d * 1024 + kt * 64 + c * 8);
    }
    __syncthreads();
    if (kt * 64 > base_w + 31) continue;       // wave fully below diagonal (uniform)
    // S = Q K^T, both groups share kf
    float4_ S[2][4];
#pragma unroll
    for (int st = 0; st < 4; ++st) {
      float4_ s0 = (float4_){0.f, 0.f, 0.f, 0.f}, s1 = s0;
      int kr = st * 16 + l16;
#pragma unroll
      for (int kc = 0; kc < 4; ++kc) {
        int c = kc * 4 + quad;
        short8 kf = *(const short8a*)&lK[kr * 128 + (c ^ (kr & 15)) * 8];
        s0 = __builtin_amdgcn_mfma_f32_16x16x32_bf16(qf[0][kc], kf, s0, 0, 0, 0);
        s1 = __builtin_amdgcn_mfma_f32_16x16x32_bf16(qf[1][kc], kf, s1, 0, 0, 0);
      }
      S[0][st] = s0; S[1][st] = s1;
    }
    // causal mask + exp + P store
#pragma unroll
    for (int g = 0; g < 2; g++) {
      int gbase = base_w + g * 16;
      if (kt * 64 + 63 > gbase) {
#pragma unroll
        for (int st = 0; st < 4; ++st)
#pragma unroll
          for (int r = 0; r < 4; r++)
            if (kt * 64 + st * 16 + l16 > gbase + quad * 4 + r) S[g][st][r] = -1e30f;
      }
#pragma unroll
      for (int st = 0; st < 4; ++st)
#pragma unroll
        for (int r = 0; r < 4; r++) {
          float pv = __expf(S[g][st][r]);
          rsacc[g][r] += pv;
          lP[wave][(g * 16 + quad * 4 + r) * 72 + st * 16 + l16] = f2b(pv);
        }
    }
    short8 pf[2][2];
#pragma unroll
    for (int g = 0; g < 2; g++)
#pragma unroll
      for (int kc2 = 0; kc2 < 2; kc2++)
        pf[g][kc2] = *(const short8a*)&lP[wave][(g * 16 + l16) * 72 + kc2 * 32 + quad * 8];
#pragma unroll
    for (int dt = 0; dt < 8; ++dt) {
      int d = dt * 16 + l16;
#pragma unroll
      for (int kc2 = 0; kc2 < 2; kc2++) {
        int c = kc2 * 4 + quad;
        short8 vf = *(const short8a*)&lV[d * 64 + (c ^ (d & 7)) * 8];
        O[0][dt] = __builtin_amdgcn_mfma_f32_16x16x32_bf16(pf[0][kc2], vf, O[0][dt], 0, 0, 0);
        O[1][dt] = __builtin_amdgcn_mfma_f32_16x16x32_bf16(pf[1][kc2], vf, O[1][dt], 0, 0, 0);
      }
    }
  }
  float hs = head_scale[h];
#pragma unroll
  for (int g = 0; g < 2; g++) {
    float l_i[4];
#pragma unroll
    for (int r = 0; r < 4; r++) {
      float rs = rsacc[g][r];
#pragma unroll
      for (int off = 8; off; off >>= 1) rs += __shfl_xor(rs, off, 64);
      l_i[r] = rs;
    }
    int qrow = base_w + g * 16 + quad * 4;
#pragma unroll
    for (int dt = 0; dt < 8; ++dt) {
      int col = h * 128 + dt * 16 + l16;
#pragma unroll
      for (int r = 0; r < 4; r++) {
        float o = O[g][dt][r] * (hs / l_i[r]);
        attn[(size_t)(b * 1024 + qrow + r) * 2048 + col] = f2b(o);
      }
    }
  }
}

// ---------- launch ----------
extern "C" void kernel_launch(void* const* d_in, const int* in_sizes, int n_in,
                              void* d_out, int out_size, void* d_ws, size_t ws_size,
                              hipStream_t stream) {
  const float* x  = (const float*)d_in[0];
  const float* Wq = (const float*)d_in[1];
  const float* Wk = (const float*)d_in[2];
  const float* Wv = (const float*)d_in[3];
  const float* Wo = (const float*)d_in[4];
  const float* hs = (const float*)d_in[5];
  float* out = (float*)d_out;
  char* ws = (char*)d_ws;
  // ws layout (64 MB total)
  short* xb    = (short*)(ws);                  // 16 MB  [4096][2048]   (reused as attn)
  short* wqkvt = (short*)(ws + 16777216);       // 12 MB  [3072][2048]
  short* wot   = (short*)(ws + 29360128);       //  8 MB  [2048][2048]
  short* qkv   = (short*)(ws + 37748736);       // 24 MB  [4096][3072]
  short* vt    = (short*)(ws + 62914560);       //  4 MB  [2048][1024]
  float* rtab  = (float*)(ws + 62914560);       // 512 KB rope table: alias vt (dead until after GEMM1)
  short* attn  = xb;                            // alias: xb dead after GEMM1

  prep<<<11008, 256, 0, stream>>>(x, Wq, Wk, Wv, Wo, xb, wqkvt, wot, rtab);
  gemm_bt<1><<<dim3(32, 24), 256, 0, stream>>>(xb, wqkvt, (void*)qkv, rtab, 4096, 3072, 2048);
  vt_build<<<dim3(16, 16), 256, 0, stream>>>(qkv, vt);
  flash<<<dim3(64, 8), 256, 0, stream>>>(qkv, vt, hs, attn);
  gemm_bt<0><<<dim3(32, 16), 256, 0, stream>>>(attn, wot, (void*)out, nullptr, 4096, 2048, 2048);
}

// Round 6
// 249.298 us; speedup vs baseline: 1.0302x; 1.0171x over previous
//
#include <hip/hip_runtime.h>

// ---------- types ----------
typedef __attribute__((ext_vector_type(8))) short short8;
typedef __attribute__((ext_vector_type(8), may_alias)) short short8a;
typedef __attribute__((ext_vector_type(4))) short short4a_ __attribute__((may_alias));
typedef __attribute__((ext_vector_type(2), may_alias)) short short2a;
typedef __attribute__((ext_vector_type(4))) float float4_;
typedef __attribute__((ext_vector_type(4), may_alias)) float float4a;
typedef __attribute__((ext_vector_type(2), may_alias)) float float2a;

__device__ __forceinline__ float b2f(short h) {
  unsigned int u = ((unsigned int)(unsigned short)h) << 16;
  return __builtin_bit_cast(float, u);
}
__device__ __forceinline__ short f2b(float f) {
  unsigned int u = __builtin_bit_cast(unsigned int, f);
  u += 0x7fffu + ((u >> 16) & 1u);   // RNE
  return (short)(unsigned short)(u >> 16);
}

#define GLOBAL_AS __attribute__((address_space(1)))
#define LDS_AS    __attribute__((address_space(3)))
__device__ __forceinline__ void async_copy16(void* lds, const void* g) {
  __builtin_amdgcn_global_load_lds((GLOBAL_AS const void*)g, (LDS_AS void*)lds, 16, 0, 0);
}

// ---------- 1. fused prep: x->bf16, Wq|Wk|Wv transpose (q-scale folded), Wo transpose, rope table ----------
// grid: [0,1536) wqkv tiles, [1536,2560) wo tiles, [2560,10752) cvt blocks, [10752,11008) rope table
__global__ __launch_bounds__(256) void prep(const float* __restrict__ x,
                                            const float* __restrict__ Wq,
                                            const float* __restrict__ Wk,
                                            const float* __restrict__ Wv,
                                            const float* __restrict__ Wo,
                                            short* __restrict__ xb,
                                            short* __restrict__ wqkvt,
                                            short* __restrict__ wot,
                                            float* __restrict__ rtab) {
  __shared__ float tile[64][65];
  int bid = blockIdx.x;
  if (bid < 1536) {                     // Wq|Wk|Wv -> [3072][2048] bf16 (B^T)
    int k0 = (bid & 31) * 64, n0 = (bid >> 5) * 64;
    for (int idx = threadIdx.x; idx < 4096; idx += 256) {
      int r = idx >> 6, cc = idx & 63;
      int n = n0 + cc;
      float v;
      if (n < 2048)      v = Wq[(size_t)(k0 + r) * 2048 + n] * 0.08838834764831845f; // fold 1/sqrt(128)
      else if (n < 2560) v = Wk[(size_t)(k0 + r) * 512 + (n - 2048)];
      else               v = Wv[(size_t)(k0 + r) * 512 + (n - 2560)];
      tile[r][cc] = v;
    }
    __syncthreads();
    for (int idx = threadIdx.x; idx < 4096; idx += 256) {
      int r = idx >> 6, cc = idx & 63;
      wqkvt[(size_t)(n0 + r) * 2048 + k0 + cc] = f2b(tile[cc][r]);
    }
  } else if (bid < 2560) {              // Wo -> [2048][2048] bf16 (B^T)
    int t = bid - 1536;
    int k0 = (t & 31) * 64, n0 = (t >> 5) * 64;
    for (int idx = threadIdx.x; idx < 4096; idx += 256) {
      int r = idx >> 6, cc = idx & 63;
      tile[r][cc] = Wo[(size_t)(k0 + r) * 2048 + n0 + cc];
    }
    __syncthreads();
    for (int idx = threadIdx.x; idx < 4096; idx += 256) {
      int r = idx >> 6, cc = idx & 63;
      wot[(size_t)(n0 + r) * 2048 + k0 + cc] = f2b(tile[cc][r]);
    }
  } else if (bid < 10752) {             // x fp32 -> bf16
    int i = (bid - 2560) * 256 + threadIdx.x;
    float4a v = ((const float4a*)x)[i];
    short4a_ o;
    o.x = f2b(v.x); o.y = f2b(v.y); o.z = f2b(v.z); o.w = f2b(v.w);
    ((short4a_*)xb)[i] = o;
  } else {                              // rope table: rtab[(pos*64+i)*2] = {cos, sin}
    int idx = (bid - 10752) * 256 + threadIdx.x;   // 0..65535
    int pos = idx >> 6, i = idx & 63;
    float inv = exp2f((float)i * -0.20762050593478f);  // 10000^(-2i/128)
    float s, c;
    sincosf((float)pos * inv, &s, &c);
    float2a cs; cs.x = c; cs.y = s;
    ((float2a*)rtab)[idx] = cs;
  }
}

// ---------- 2. GEMM  C[M][N] = A[M][K] * B^T[N][K] ----------
// MODE 0: fp32 direct store.
// MODE 1: bf16; n0<2560 -> fused RoPE (table, loads hoisted) -> qkv; n0>=2560 -> transposed V -> vt.
// 128x128 tile, BK=64, global_load_lds(16B), XOR chunk swizzle (chunk' = chunk ^ (row&7))
template <int MODE>
__global__ __launch_bounds__(256, 2)
void gemm_bt(const short* __restrict__ A, const short* __restrict__ B,
             void* __restrict__ Cv, const float* __restrict__ rtab,
             short* __restrict__ vt, int M, int N, int K) {
  __shared__ alignas(16) short lsm[MODE == 1 ? 16896 : 16384];
  short* lA = lsm;
  short* lB = lsm + 8192;
  const int tid = threadIdx.x;
  const int wave = tid >> 6, lane = tid & 63;
  const int quad = lane >> 4, l16 = lane & 15;
  const int m0 = blockIdx.x * 128, n0 = blockIdx.y * 128;
  const int wm = (wave >> 1) * 64, wn = (wave & 1) * 64;
  float4_ acc[4][4];
#pragma unroll
  for (int i = 0; i < 4; i++)
#pragma unroll
    for (int j = 0; j < 4; j++) acc[i][j] = (float4_){0.f, 0.f, 0.f, 0.f};
  const int nK = K >> 6;
  const int srow = lane >> 3, slot = lane & 7;
  for (int kt = 0; kt < nK; ++kt) {
    __syncthreads();
#pragma unroll
    for (int cth = 0; cth < 4; ++cth) {
      int rb = wave * 32 + cth * 8;
      int r = rb + srow;
      int c = slot ^ (r & 7);
      async_copy16(&lA[rb * 64], A + (size_t)(m0 + r) * K + kt * 64 + c * 8);
      async_copy16(&lB[rb * 64], B + (size_t)(n0 + r) * K + kt * 64 + c * 8);
    }
    __syncthreads();
#pragma unroll
    for (int kc = 0; kc < 2; ++kc) {
      short8 af[4], bf[4];
      int cch = kc * 4 + quad;
#pragma unroll
      for (int mt = 0; mt < 4; ++mt) {
        int ar = wm + mt * 16 + l16;
        af[mt] = *(const short8a*)&lA[ar * 64 + (cch ^ (ar & 7)) * 8];
      }
#pragma unroll
      for (int nt = 0; nt < 4; ++nt) {
        int br = wn + nt * 16 + l16;
        bf[nt] = *(const short8a*)&lB[br * 64 + (cch ^ (br & 7)) * 8];
      }
#pragma unroll
      for (int mt = 0; mt < 4; ++mt)
#pragma unroll
        for (int nt = 0; nt < 4; ++nt)
          acc[mt][nt] = __builtin_amdgcn_mfma_f32_16x16x32_bf16(af[mt], bf[nt], acc[mt][nt], 0, 0, 0);
    }
  }
  if (MODE == 1) {
    const bool isRope = (n0 < 2560);    // block-uniform
    __syncthreads();                    // staging LDS now dead
    short* lC = lsm;                    // [128][132] bf16
    const int posBase = m0 & 1023;
    float4a tv[16];
    if (isRope) {                       // hoist table loads: latency hidden behind lC writes + barrier
#pragma unroll
      for (int it = 0; it < 16; ++it) {
        int idx = it * 256 + tid;
        int row = idx >> 5, c2 = (idx & 31) * 2;
        tv[it] = *(const float4a*)&rtab[((size_t)(posBase + row) * 64 + c2) * 2];
      }
    }
#pragma unroll
    for (int mt = 0; mt < 4; ++mt)
#pragma unroll
      for (int nt = 0; nt < 4; ++nt)
#pragma unroll
        for (int r = 0; r < 4; r++)
          lC[(wm + mt * 16 + quad * 4 + r) * 132 + wn + nt * 16 + l16] = f2b(acc[mt][nt][r]);
    __syncthreads();
    if (isRope) {
      short* Cb = (short*)Cv;
#pragma unroll
      for (int it = 0; it < 16; ++it) {
        int idx = it * 256 + tid;       // 0..4095
        int row = idx >> 5;             // 0..127
        int c2 = (idx & 31) * 2;        // pair indices c2, c2+1 (in [0,64))
        short2a t1 = *(const short2a*)&lC[row * 132 + c2];
        short2a t2 = *(const short2a*)&lC[row * 132 + c2 + 64];
        float t1a = b2f(t1.x), t1b = b2f(t1.y);
        float t2a = b2f(t2.x), t2b = b2f(t2.y);
        float4a t = tv[it];             // ca,sa,cb,sb
        short2a o1, o2;
        o1.x = f2b(t1a * t.x - t2a * t.y); o1.y = f2b(t1b * t.z - t2b * t.w);
        o2.x = f2b(t2a * t.x + t1a * t.y); o2.y = f2b(t2b * t.z + t1b * t.w);
        size_t base = (size_t)(m0 + row) * N + n0;
        *(short2a*)&Cb[base + c2] = o1;
        *(short2a*)&Cb[base + c2 + 64] = o2;
      }
    } else {
      // V block: transposed store into vt[(b*4+kv)*128+d][seq]
      const int bkv = (m0 >> 10) * 4 + ((n0 - 2560) >> 7);
#pragma unroll
      for (int it = 0; it < 8; ++it) {
        int idx = it * 256 + tid;       // 0..2047
        int d = idx >> 4, jc = idx & 15;
        short8 v;
#pragma unroll
        for (int k = 0; k < 8; ++k) v[k] = lC[(jc * 8 + k) * 132 + d];
        *(short8a*)&vt[((size_t)(bkv * 128 + d)) * 1024 + posBase + jc * 8] = v;
      }
    }
  } else {
#pragma unroll
    for (int mt = 0; mt < 4; ++mt)
#pragma unroll
      for (int nt = 0; nt < 4; ++nt) {
        int row = m0 + wm + mt * 16 + quad * 4;
        int col = n0 + wn + nt * 16 + l16;
        float4_ v = acc[mt][nt];
        float* Cf = (float*)Cv;
#pragma unroll
        for (int r = 0; r < 4; r++) Cf[(size_t)(row + r) * N + col] = v[r];
      }
  }
}

// ---------- 3. GQA causal flash attention (no-max softmax; 128-row Q tiles) ----------
// grid (64 = b*16+h, 8 qtiles reversed), 256 threads = 4 waves x (2 groups x 16 q-rows)
__global__ __launch_bounds__(256, 2)
void flash(const short* __restrict__ qkv, const short* __restrict__ vt,
           const float* __restrict__ head_scale, short* __restrict__ attn) {
  __shared__ alignas(16) short lK[64 * 128];   // [krow][d-chunk swizzled]
  __shared__ alignas(16) short lV[128 * 64];   // [d][krow-chunk swizzled]
  __shared__ alignas(16) short lP[4][32 * 72]; // per-wave P (32 rows), padded stride 72
  const int tid = threadIdx.x, wave = tid >> 6, lane = tid & 63;
  const int quad = lane >> 4, l16 = lane & 15;
  const int bh = blockIdx.x, b = bh >> 4, h = bh & 15, kv = h >> 2;
  const int qt = 7 - blockIdx.y;               // heavy blocks first
  const int base_w = qt * 128 + wave * 32;     // wave's first q-row
  short8 qf[2][4];
#pragma unroll
  for (int g = 0; g < 2; g++) {
    int qrow = base_w + g * 16 + l16;
    const short* qp = qkv + (size_t)(b * 1024 + qrow) * 3072 + h * 128;
#pragma unroll
    for (int kc = 0; kc < 4; kc++) qf[g][kc] = *(const short8a*)(qp + kc * 32 + quad * 8);
  }
  float4_ O[2][8];
#pragma unroll
  for (int g = 0; g < 2; g++)
#pragma unroll
    for (int i = 0; i < 8; i++) O[g][i] = (float4_){0.f, 0.f, 0.f, 0.f};
  float rsacc[2][4] = {{0.f, 0.f, 0.f, 0.f}, {0.f, 0.f, 0.f, 0.f}};
  const size_t kbase = (size_t)(b * 1024) * 3072 + 2048 + kv * 128;
  const size_t vbase = (size_t)((b * 4 + kv) * 128) * 1024;
  const int slot16 = lane & 15, rr4 = lane >> 4;
  const int slot8 = lane & 7, dr8 = lane >> 3;
  const int nkt = 2 * qt + 2;
  for (int kt = 0; kt < nkt; ++kt) {
    __syncthreads();
#pragma unroll
    for (int cc = 0; cc < 4; ++cc) {           // K tile: 64 rows x 128 d
      int rb = wave * 16 + cc * 4;
      int r = rb + rr4;
      int c = slot16 ^ (r & 15);
      async_copy16(&lK[rb * 128], qkv + kbase + (size_t)(kt * 64 + r) * 3072 + c * 8);
    }
#pragma unroll
    for (int cc = 0; cc < 4; ++cc) {           // V tile: 128 d x 64 rows
      int db = wave * 32 + cc * 8;
      int d = db + dr8;
      int c = slot8 ^ (d & 7);
      async_copy16(&lV[db * 64], vt + vbase + (size_t)d * 1024 + kt * 64 + c * 8);
    }
    __syncthreads();
    if (kt * 64 > base_w + 31) continue;       // wave fully below diagonal (uniform)
    // S = Q K^T, both groups share kf
    float4_ S[2][4];
#pragma unroll
    for (int st = 0; st < 4; ++st) {
      float4_ s0 = (float4_){0.f, 0.f, 0.f, 0.f}, s1 = s0;
      int kr = st * 16 + l16;
#pragma unroll
      for (int kc = 0; kc < 4; ++kc) {
        int c = kc * 4 + quad;
        short8 kf = *(const short8a*)&lK[kr * 128 + (c ^ (kr & 15)) * 8];
        s0 = __builtin_amdgcn_mfma_f32_16x16x32_bf16(qf[0][kc], kf, s0, 0, 0, 0);
        s1 = __builtin_amdgcn_mfma_f32_16x16x32_bf16(qf[1][kc], kf, s1, 0, 0, 0);
      }
      S[0][st] = s0; S[1][st] = s1;
    }
    // causal mask + exp + P store
#pragma unroll
    for (int g = 0; g < 2; g++) {
      int gbase = base_w + g * 16;
      if (kt * 64 + 63 > gbase) {
#pragma unroll
        for (int st = 0; st < 4; ++st)
#pragma unroll
          for (int r = 0; r < 4; r++)
            if (kt * 64 + st * 16 + l16 > gbase + quad * 4 + r) S[g][st][r] = -1e30f;
      }
#pragma unroll
      for (int st = 0; st < 4; ++st)
#pragma unroll
        for (int r = 0; r < 4; r++) {
          float pv = __expf(S[g][st][r]);
          rsacc[g][r] += pv;
          lP[wave][(g * 16 + quad * 4 + r) * 72 + st * 16 + l16] = f2b(pv);
        }
    }
    short8 pf[2][2];
#pragma unroll
    for (int g = 0; g < 2; g++)
#pragma unroll
      for (int kc2 = 0; kc2 < 2; kc2++)
        pf[g][kc2] = *(const short8a*)&lP[wave][(g * 16 + l16) * 72 + kc2 * 32 + quad * 8];
#pragma unroll
    for (int dt = 0; dt < 8; ++dt) {
      int d = dt * 16 + l16;
#pragma unroll
      for (int kc2 = 0; kc2 < 2; kc2++) {
        int c = kc2 * 4 + quad;
        short8 vf = *(const short8a*)&lV[d * 64 + (c ^ (d & 7)) * 8];
        O[0][dt] = __builtin_amdgcn_mfma_f32_16x16x32_bf16(pf[0][kc2], vf, O[0][dt], 0, 0, 0);
        O[1][dt] = __builtin_amdgcn_mfma_f32_16x16x32_bf16(pf[1][kc2], vf, O[1][dt], 0, 0, 0);
      }
    }
  }
  float hs = head_scale[h];
#pragma unroll
  for (int g = 0; g < 2; g++) {
    float l_i[4];
#pragma unroll
    for (int r = 0; r < 4; r++) {
      float rs = rsacc[g][r];
#pragma unroll
      for (int off = 8; off; off >>= 1) rs += __shfl_xor(rs, off, 64);
      l_i[r] = rs;
    }
    int qrow = base_w + g * 16 + quad * 4;
#pragma unroll
    for (int dt = 0; dt < 8; ++dt) {
      int col = h * 128 + dt * 16 + l16;
#pragma unroll
      for (int r = 0; r < 4; r++) {
        float o = O[g][dt][r] * (hs / l_i[r]);
        attn[(size_t)(b * 1024 + qrow + r) * 2048 + col] = f2b(o);
      }
    }
  }
}

// ---------- launch ----------
extern "C" void kernel_launch(void* const* d_in, const int* in_sizes, int n_in,
                              void* d_out, int out_size, void* d_ws, size_t ws_size,
                              hipStream_t stream) {
  const float* x  = (const float*)d_in[0];
  const float* Wq = (const float*)d_in[1];
  const float* Wk = (const float*)d_in[2];
  const float* Wv = (const float*)d_in[3];
  const float* Wo = (const float*)d_in[4];
  const float* hs = (const float*)d_in[5];
  float* out = (float*)d_out;
  char* ws = (char*)d_ws;
  // ws layout (64 MB total)
  short* xb    = (short*)(ws);                  // 16 MB  [4096][2048]   (reused as attn)
  short* wqkvt = (short*)(ws + 16777216);       // 12 MB  [3072][2048]
  short* wot   = (short*)(ws + 29360128);       //  8 MB  [2048][2048]
  short* qkv   = (short*)(ws + 37748736);       // 24 MB  [4096][3072] (V cols unused)
  short* vt    = (short*)(ws + 62914560);       //  4 MB  [2048][1024]
  short* attn  = xb;                            // alias: xb dead after GEMM1
  // rope table lives in d_out's tail: d_out (32 MB fp32) is dead until GEMM2 fully overwrites it
  float* rtab  = out + 8257536;                 // 512 KB = 131072 floats

  prep<<<11008, 256, 0, stream>>>(x, Wq, Wk, Wv, Wo, xb, wqkvt, wot, rtab);
  gemm_bt<1><<<dim3(32, 24), 256, 0, stream>>>(xb, wqkvt, (void*)qkv, rtab, vt, 4096, 3072, 2048);
  flash<<<dim3(64, 8), 256, 0, stream>>>(qkv, vt, hs, attn);
  gemm_bt<0><<<dim3(32, 16), 256, 0, stream>>>(attn, wot, (void*)out, nullptr, nullptr, 4096, 2048, 2048);
}